// Round 3
// baseline (360.207 us; speedup 1.0000x reference)
//
#include <hip/hip_runtime.h>

// Problem constants (from setup_inputs)
constexpr int B = 2, V = 5, C = 32, H = 256, W = 320, D = 4;
constexpr int HW = H * W;
constexpr int NTHREAD = B * HW * D;    // 655360: one thread per (pixel, d)
constexpr int BLK = 256;
constexpr int NBLK = NTHREAD / BLK;    // 2560, divisible by 8 (XCD swizzle OK)

// rot (9) + trans (3) per (b, src view v=1..4), fp32 (bit-exact ref replication)
__device__ float g_rt[B * (V - 1) * 12];

// combine(): upd = K3 @ E[:3,:4]. XLA-CPU naive small-dot emitter semantics.
__device__ void combine_np(const float* __restrict__ proj, int b, int v, float Mo[4][4]) {
    const float* E = proj + ((size_t)(b * V + v) * 2 + 0) * 16;
    const float* K = proj + ((size_t)(b * V + v) * 2 + 1) * 16;
    for (int i = 0; i < 3; i++)
        for (int j = 0; j < 4; j++) {
            float acc = __fadd_rn(0.0f, __fmul_rn(K[i * 4 + 0], E[0 * 4 + j]));
            acc = __fadd_rn(acc, __fmul_rn(K[i * 4 + 1], E[1 * 4 + j]));
            acc = __fadd_rn(acc, __fmul_rn(K[i * 4 + 2], E[2 * 4 + j]));
            Mo[i][j] = acc;
        }
    for (int j = 0; j < 4; j++) Mo[3][j] = E[3 * 4 + j];
}

// ---------------------------------------------------------------------------
// Setup (unchanged, bit-exact strti2 + naive-emitter chains).
// ---------------------------------------------------------------------------
__global__ void setup_proj(const float* __restrict__ proj) {
    int t = threadIdx.x;
    if (t >= B * (V - 1)) return;
    int b = t / (V - 1);
    int v = t % (V - 1) + 1;

    float R[4][4], S[4][4];
    combine_np(proj, b, 0, R);
    combine_np(proj, b, v, S);

    float I4[4][4];
    for (int i = 0; i < 4; i++)
        for (int j = 0; j < 4; j++) I4[i][j] = 0.0f;

    float d0 = __fdiv_rn(1.0f, R[0][0]);
    I4[0][0] = d0;
    float d1 = __fdiv_rn(1.0f, R[1][1]);
    I4[1][1] = d1;
    {
        float x0 = R[0][1];
        if (x0 != 0.0f) x0 = __fmul_rn(x0, I4[0][0]);
        I4[0][1] = __fmul_rn(x0, -d1);
    }
    float d2 = __fdiv_rn(1.0f, R[2][2]);
    I4[2][2] = d2;
    {
        float x0 = R[0][2], x1 = R[1][2];
        if (x0 != 0.0f) x0 = __fmul_rn(x0, I4[0][0]);
        if (x1 != 0.0f) {
            x0 = __fadd_rn(x0, __fmul_rn(x1, I4[0][1]));
            x1 = __fmul_rn(x1, I4[1][1]);
        }
        I4[0][2] = __fmul_rn(x0, -d2);
        I4[1][2] = __fmul_rn(x1, -d2);
    }
    float d3 = __fdiv_rn(1.0f, R[3][3]);
    I4[3][3] = d3;
    {
        float x0 = R[0][3], x1 = R[1][3], x2 = R[2][3];
        if (x0 != 0.0f) x0 = __fmul_rn(x0, I4[0][0]);
        if (x1 != 0.0f) {
            x0 = __fadd_rn(x0, __fmul_rn(x1, I4[0][1]));
            x1 = __fmul_rn(x1, I4[1][1]);
        }
        if (x2 != 0.0f) {
            x0 = __fadd_rn(x0, __fmul_rn(x2, I4[0][2]));
            x1 = __fadd_rn(x1, __fmul_rn(x2, I4[1][2]));
            x2 = __fmul_rn(x2, I4[2][2]);
        }
        I4[0][3] = __fmul_rn(x0, -d3);
        I4[1][3] = __fmul_rn(x1, -d3);
        I4[2][3] = __fmul_rn(x2, -d3);
    }

    float P[3][4];
    for (int i = 0; i < 3; i++)
        for (int k = 0; k < 4; k++) {
            float acc = 0.0f;
            for (int j = 0; j < 4; j++)
                acc = __fadd_rn(acc, __fmul_rn(S[i][j], I4[j][k]));
            P[i][k] = acc;
        }

    float* out = g_rt + t * 12;
    out[0] = P[0][0]; out[1] = P[0][1]; out[2] = P[0][2];
    out[3] = P[1][0]; out[4] = P[1][1]; out[5] = P[1][2];
    out[6] = P[2][0]; out[7] = P[2][1]; out[8] = P[2][2];
    out[9] = P[0][3]; out[10] = P[1][3]; out[11] = P[2][3];
}

// ---------------------------------------------------------------------------
// R3: R1's thread structure (one thread per (b,d,h,w), 17 loads/c-iter,
// scalar s/q, ~40 VGPR, 10240 waves) + the ONE change that captures R2's
// traffic win without killing parallelism: d lives in the LOW 2 BITS of the
// thread index. Lane group {4k..4k+3} = one pixel x 4 depths. Adjacent-depth
// taps differ by only ~4px parallax, so within each tap load instruction the
// 64 lanes (16 pixels x 4 depths) cluster into the SAME cache lines -> the
// 4x cross-d re-fetch of R0/R1 (396MB) dedups in the coalescer/L1, while
// wave count stays at 10240 (R2's folding got the same reuse but at 2560
// waves / occ 17% -> latency-bound, 193us).
// Evidence: R1 150us @ 396MB fetch / occ 57%; R2 193us @ 66MB fetch / occ
// 17%. The wins are separable; this kernel takes both.
// Mask: each lane owns its (v,d) nonzero bits completely -> popc + 2x
// shfl_xor sum over the 4-lane group, lane d==0 stores (atomic+memset gone).
// Numerics: identical op sequence per (pixel,v,d,c); per-channel accumulation
// order unchanged (ref, then v=1..4) -> bit-identical to the passing R1.
// ---------------------------------------------------------------------------
__global__ __launch_bounds__(256) void warp_var(
    const float* __restrict__ feats,
    const float* __restrict__ depthv,
    float* __restrict__ var_out,
    float* __restrict__ mask_out)
{
    // bijective chunked XCD swizzle (NBLK % 8 == 0): contiguous pixel chunk
    // per XCD -> tap working set per XCD fits its 4MB L2.
    int bid = blockIdx.x;
    int bswz = (bid & 7) * (NBLK / 8) + (bid >> 3);
    int t = bswz * BLK + threadIdx.x;

    int d = t & 3;           // depth plane in the low lane bits
    int p = t >> 2;          // pixel index in [0, B*HW)
    int hw = p % HW;
    int b = p / HW;
    int w = hw % W;
    int h = hw / W;

    float depth = depthv[(size_t)(b * D + d) * HW + hw];

    const float xf = (float)w, yf = (float)h;
    const float hwX = 0.5f * (float)(W - 1);  // 159.5
    const float hwY = 0.5f * (float)(H - 1);  // 127.5
    const float rcpX = 1.0f / 159.5f;  // fl(1/159.5), compile-time RN fold
    const float rcpY = 1.0f / 127.5f;  // fl(1/127.5)

    // Per-view tap state: 4 element offsets (c=0 plane) + 4 combined weights.
    int   toff[V - 1][4];
    float twt[V - 1][4];

#pragma unroll
    for (int v = 1; v < V; v++) {
        const float* P = g_rt + ((size_t)b * (V - 1) + (v - 1)) * 12;
        // Eigen FMA sweeps: fma(P1,y, fma(P0,x, 0)) then fma(P2,1,acc)=fadd
        float rx = __fadd_rn(__fmaf_rn(P[1], yf, __fmul_rn(P[0], xf)), P[2]);
        float ry = __fadd_rn(__fmaf_rn(P[4], yf, __fmul_rn(P[3], xf)), P[5]);
        float rz = __fadd_rn(__fmaf_rn(P[7], yf, __fmul_rn(P[6], xf)), P[8]);
        // pxyz = rot_xyz * d + trans : two separate ops (no contract FMF)
        float px = __fadd_rn(__fmul_rn(rx, depth), P[9]);
        float py = __fadd_rn(__fmul_rn(ry, depth), P[10]);
        float pz = __fadd_rn(__fmul_rn(rz, depth), P[11]);
        float gx = __fdiv_rn(px, pz);
        float gy = __fdiv_rn(py, pz);
        // XLA: divide-by-constant -> multiply-by-folded-reciprocal
        float nx = __fadd_rn(__fmul_rn(gx, rcpX), -1.0f);
        float ny = __fadd_rn(__fmul_rn(gy, rcpY), -1.0f);
        // round trip kept intact (no float reassociation by default)
        float x = __fmul_rn(__fadd_rn(nx, 1.0f), hwX);
        float y = __fmul_rn(__fadd_rn(ny, 1.0f), hwY);

        float x0 = floorf(x), y0 = floorf(y);
        float x1 = x0 + 1.0f, y1 = y0 + 1.0f;

        float wx0 = __fadd_rn(1.0f, -fabsf(__fadd_rn(x, -x0)));
        float wx1 = __fadd_rn(1.0f, -fabsf(__fadd_rn(x, -x1)));
        float wy0 = __fadd_rn(1.0f, -fabsf(__fadd_rn(y, -y0)));
        float wy1 = __fadd_rn(1.0f, -fabsf(__fadd_rn(y, -y1)));

        float vx0 = (x0 >= 0.0f && x0 <= (float)(W - 1)) ? 1.0f : 0.0f;
        float vx1 = (x1 >= 0.0f && x1 <= (float)(W - 1)) ? 1.0f : 0.0f;
        float vy0 = (y0 >= 0.0f && y0 <= (float)(H - 1)) ? 1.0f : 0.0f;
        float vy1 = (y1 >= 0.0f && y1 <= (float)(H - 1)) ? 1.0f : 0.0f;

        twt[v - 1][0] = __fmul_rn(__fmul_rn(wx0, wy0), __fmul_rn(vx0, vy0));
        twt[v - 1][1] = __fmul_rn(__fmul_rn(wx1, wy0), __fmul_rn(vx1, vy0));
        twt[v - 1][2] = __fmul_rn(__fmul_rn(wx0, wy1), __fmul_rn(vx0, vy1));
        twt[v - 1][3] = __fmul_rn(__fmul_rn(wx1, wy1), __fmul_rn(vx1, vy1));

        int xi0 = (int)fminf(fmaxf(x0, 0.0f), (float)(W - 1));
        int xi1 = (int)fminf(fmaxf(x1, 0.0f), (float)(W - 1));
        int yi0 = (int)fminf(fmaxf(y0, 0.0f), (float)(H - 1));
        int yi1 = (int)fminf(fmaxf(y1, 0.0f), (float)(H - 1));

        int vb = (b * V + v) * C * HW;  // < 2^25, int32-safe
        toff[v - 1][0] = vb + yi0 * W + xi0;
        toff[v - 1][1] = vb + yi0 * W + xi1;
        toff[v - 1][2] = vb + yi1 * W + xi0;
        toff[v - 1][3] = vb + yi1 * W + xi1;
    }

    const int rb = b * V * C * HW + hw;  // ref view, c=0 plane
    const float inv_v = 1.0f / (float)V;
    // out layout [B,C,D,H,W]
    const size_t obase = ((size_t)b * C * D + d) * HW + (size_t)hw;

    int nzmask = 0;  // bit v set iff any channel of view v+1 sampled nonzero

#pragma unroll 2
    for (int c = 0; c < C; c++) {
        const int cofs = c * HW;
        // 17 independent loads; lanes 4k..4k+3 (4 depths, same pixel) hit the
        // same cache lines -> intra-instruction dedup of the cross-d traffic.
        float rv = feats[rb + cofs];
        float s = rv;
        float q = rv * rv;
#pragma unroll
        for (int v = 0; v < V - 1; v++) {
            float f00 = feats[toff[v][0] + cofs];
            float f10 = feats[toff[v][1] + cofs];
            float f01 = feats[toff[v][2] + cofs];
            float f11 = feats[toff[v][3] + cofs];
            // zeroness is weight-structural (all-OOB => all wt exactly 0)
            float val = twt[v][0] * f00 + twt[v][1] * f10 + twt[v][2] * f01 + twt[v][3] * f11;
            nzmask |= (val != 0.0f) ? (1 << v) : 0;
            s += val;
            q += val * val;
        }
        // variance = sq/V - (sum/V)^2
        float sm = s * inv_v;
        float vv = q * inv_v - sm * sm;
        // streaming 86MB output: keep it out of the gather working set
        __builtin_nontemporal_store(vv, &var_out[obase + (size_t)c * (D * HW)]);
    }

    // cv_mask[b,h,w] = sum over (v,d) of any-channel-nonzero. Each lane owns
    // its d completely: popc, then sum across the 4-lane (4-depth) group.
    int m = __popc(nzmask);
    m += __shfl_xor(m, 1);
    m += __shfl_xor(m, 2);
    if (d == 0) mask_out[(size_t)b * HW + hw] = (float)m;
}

extern "C" void kernel_launch(void* const* d_in, const int* in_sizes, int n_in,
                              void* d_out, int out_size, void* d_ws, size_t ws_size,
                              hipStream_t stream) {
    const float* feats = (const float*)d_in[0];
    const float* proj = (const float*)d_in[1];
    const float* depthv = (const float*)d_in[2];

    float* var = (float*)d_out;
    float* mask = var + (size_t)B * C * D * HW;

    setup_proj<<<1, 64, 0, stream>>>(proj);

    warp_var<<<NBLK, BLK, 0, stream>>>(feats, depthv, var, mask);
}

// Round 4
// 275.884 us; speedup vs baseline: 1.3056x; 1.3056x over previous
//
#include <hip/hip_runtime.h>

// Problem constants (from setup_inputs)
constexpr int B = 2, V = 5, C = 32, H = 256, W = 320, D = 4;
constexpr int HW = H * W;
constexpr int BLK = 256;               // 4 waves = 4 depth planes
constexpr int NBLK = B * HW / 64;      // 2560 chunks of 64 pixels; %8==0

// rot (9) + trans (3) per (b, src view v=1..4), fp32 (bit-exact ref replication)
__device__ float g_rt[B * (V - 1) * 12];

// combine(): upd = K3 @ E[:3,:4]. XLA-CPU naive small-dot emitter semantics.
__device__ void combine_np(const float* __restrict__ proj, int b, int v, float Mo[4][4]) {
    const float* E = proj + ((size_t)(b * V + v) * 2 + 0) * 16;
    const float* K = proj + ((size_t)(b * V + v) * 2 + 1) * 16;
    for (int i = 0; i < 3; i++)
        for (int j = 0; j < 4; j++) {
            float acc = __fadd_rn(0.0f, __fmul_rn(K[i * 4 + 0], E[0 * 4 + j]));
            acc = __fadd_rn(acc, __fmul_rn(K[i * 4 + 1], E[1 * 4 + j]));
            acc = __fadd_rn(acc, __fmul_rn(K[i * 4 + 2], E[2 * 4 + j]));
            Mo[i][j] = acc;
        }
    for (int j = 0; j < 4; j++) Mo[3][j] = E[3 * 4 + j];
}

// ---------------------------------------------------------------------------
// Setup (unchanged, bit-exact strti2 + naive-emitter chains).
// ---------------------------------------------------------------------------
__global__ void setup_proj(const float* __restrict__ proj) {
    int t = threadIdx.x;
    if (t >= B * (V - 1)) return;
    int b = t / (V - 1);
    int v = t % (V - 1) + 1;

    float R[4][4], S[4][4];
    combine_np(proj, b, 0, R);
    combine_np(proj, b, v, S);

    float I4[4][4];
    for (int i = 0; i < 4; i++)
        for (int j = 0; j < 4; j++) I4[i][j] = 0.0f;

    float d0 = __fdiv_rn(1.0f, R[0][0]);
    I4[0][0] = d0;
    float d1 = __fdiv_rn(1.0f, R[1][1]);
    I4[1][1] = d1;
    {
        float x0 = R[0][1];
        if (x0 != 0.0f) x0 = __fmul_rn(x0, I4[0][0]);
        I4[0][1] = __fmul_rn(x0, -d1);
    }
    float d2 = __fdiv_rn(1.0f, R[2][2]);
    I4[2][2] = d2;
    {
        float x0 = R[0][2], x1 = R[1][2];
        if (x0 != 0.0f) x0 = __fmul_rn(x0, I4[0][0]);
        if (x1 != 0.0f) {
            x0 = __fadd_rn(x0, __fmul_rn(x1, I4[0][1]));
            x1 = __fmul_rn(x1, I4[1][1]);
        }
        I4[0][2] = __fmul_rn(x0, -d2);
        I4[1][2] = __fmul_rn(x1, -d2);
    }
    float d3 = __fdiv_rn(1.0f, R[3][3]);
    I4[3][3] = d3;
    {
        float x0 = R[0][3], x1 = R[1][3], x2 = R[2][3];
        if (x0 != 0.0f) x0 = __fmul_rn(x0, I4[0][0]);
        if (x1 != 0.0f) {
            x0 = __fadd_rn(x0, __fmul_rn(x1, I4[0][1]));
            x1 = __fmul_rn(x1, I4[1][1]);
        }
        if (x2 != 0.0f) {
            x0 = __fadd_rn(x0, __fmul_rn(x2, I4[0][2]));
            x1 = __fadd_rn(x1, __fmul_rn(x2, I4[1][2]));
            x2 = __fmul_rn(x2, I4[2][2]);
        }
        I4[0][3] = __fmul_rn(x0, -d3);
        I4[1][3] = __fmul_rn(x1, -d3);
        I4[2][3] = __fmul_rn(x2, -d3);
    }

    float P[3][4];
    for (int i = 0; i < 3; i++)
        for (int k = 0; k < 4; k++) {
            float acc = 0.0f;
            for (int j = 0; j < 4; j++)
                acc = __fadd_rn(acc, __fmul_rn(S[i][j], I4[j][k]));
            P[i][k] = acc;
        }

    float* out = g_rt + t * 12;
    out[0] = P[0][0]; out[1] = P[0][1]; out[2] = P[0][2];
    out[3] = P[1][0]; out[4] = P[1][1]; out[5] = P[1][2];
    out[6] = P[2][0]; out[7] = P[2][1]; out[8] = P[2][2];
    out[9] = P[0][3]; out[10] = P[1][3]; out[11] = P[2][3];
}

// ---------------------------------------------------------------------------
// R4: R1's wave shape (the proven-fast one: 64 consecutive same-d pixels per
// wave -> minimal cache lines per gather instr, full-line 256B stores) with
// ONE mapping change: the 4 waves of a block = the 4 depth planes of the
// SAME 64-pixel chunk. Evidence across R1/R2/R3:
//   R1 (d-partitioned grid):   150us, fetch 396MB (4x cross-d refetch) @3.2TB/s
//   R2 (d folded in thread):   193us, fetch  66MB, occ 17% -> latency-bound
//   R3 (d in low lane bits):   233us, fetch  55MB @0.7TB/s -> line-txn bound
//     (d-lanes hit different source rows -> ~2x lines/instr; 64B partial-line
//      stores -> WRITE 84->110MB)
// The low-traffic variants changed the WAVE SHAPE and hit an internal wall.
// R4 changes WHERE the reuse happens instead: the 4 depth-waves run in
// lockstep on the same CU, touching near-identical source lines (~2.5px
// parallax/step) -> cross-d dedup in L1 (per-c working set ~14KB << 32KB L1),
// per-instruction patterns identical to R1. Chunk-contiguous XCD swizzle
// keeps adjacent-chunk halo reuse in the XCD L2.
// Mask: LDS reduce across the 4 depth-waves (atomic + memset gone).
// Numerics: per-thread op sequence bit-identical to R1/R3 (both passed).
// ---------------------------------------------------------------------------
__global__ __launch_bounds__(256) void warp_var(
    const float* __restrict__ feats,
    const float* __restrict__ depthv,
    float* __restrict__ var_out,
    float* __restrict__ mask_out)
{
    // chunk-contiguous bijective XCD swizzle (NBLK % 8 == 0): XCD x gets
    // chunks [x*320, (x+1)*320) in order -> halo overlap stays L2-local.
    int bid = blockIdx.x;
    int chunk = (bid & 7) * (NBLK / 8) + (bid >> 3);

    int lane = threadIdx.x & 63;
    int d = threadIdx.x >> 6;        // wave index == depth plane
    int pix = chunk * 64 + lane;     // global pixel in [0, B*HW)
    int hw = pix % HW;
    int b = pix / HW;
    int w = hw % W;
    int h = hw / W;

    float depth = depthv[(size_t)(b * D + d) * HW + hw];

    const float xf = (float)w, yf = (float)h;
    const float hwX = 0.5f * (float)(W - 1);  // 159.5
    const float hwY = 0.5f * (float)(H - 1);  // 127.5
    const float rcpX = 1.0f / 159.5f;  // fl(1/159.5), compile-time RN fold
    const float rcpY = 1.0f / 127.5f;  // fl(1/127.5)

    // Per-view tap state: 4 element offsets (c=0 plane) + 4 combined weights.
    int   toff[V - 1][4];
    float twt[V - 1][4];

#pragma unroll
    for (int v = 1; v < V; v++) {
        const float* P = g_rt + ((size_t)b * (V - 1) + (v - 1)) * 12;
        // Eigen FMA sweeps: fma(P1,y, fma(P0,x, 0)) then fma(P2,1,acc)=fadd
        float rx = __fadd_rn(__fmaf_rn(P[1], yf, __fmul_rn(P[0], xf)), P[2]);
        float ry = __fadd_rn(__fmaf_rn(P[4], yf, __fmul_rn(P[3], xf)), P[5]);
        float rz = __fadd_rn(__fmaf_rn(P[7], yf, __fmul_rn(P[6], xf)), P[8]);
        // pxyz = rot_xyz * d + trans : two separate ops (no contract FMF)
        float px = __fadd_rn(__fmul_rn(rx, depth), P[9]);
        float py = __fadd_rn(__fmul_rn(ry, depth), P[10]);
        float pz = __fadd_rn(__fmul_rn(rz, depth), P[11]);
        float gx = __fdiv_rn(px, pz);
        float gy = __fdiv_rn(py, pz);
        // XLA: divide-by-constant -> multiply-by-folded-reciprocal
        float nx = __fadd_rn(__fmul_rn(gx, rcpX), -1.0f);
        float ny = __fadd_rn(__fmul_rn(gy, rcpY), -1.0f);
        // round trip kept intact (no float reassociation by default)
        float x = __fmul_rn(__fadd_rn(nx, 1.0f), hwX);
        float y = __fmul_rn(__fadd_rn(ny, 1.0f), hwY);

        float x0 = floorf(x), y0 = floorf(y);
        float x1 = x0 + 1.0f, y1 = y0 + 1.0f;

        float wx0 = __fadd_rn(1.0f, -fabsf(__fadd_rn(x, -x0)));
        float wx1 = __fadd_rn(1.0f, -fabsf(__fadd_rn(x, -x1)));
        float wy0 = __fadd_rn(1.0f, -fabsf(__fadd_rn(y, -y0)));
        float wy1 = __fadd_rn(1.0f, -fabsf(__fadd_rn(y, -y1)));

        float vx0 = (x0 >= 0.0f && x0 <= (float)(W - 1)) ? 1.0f : 0.0f;
        float vx1 = (x1 >= 0.0f && x1 <= (float)(W - 1)) ? 1.0f : 0.0f;
        float vy0 = (y0 >= 0.0f && y0 <= (float)(H - 1)) ? 1.0f : 0.0f;
        float vy1 = (y1 >= 0.0f && y1 <= (float)(H - 1)) ? 1.0f : 0.0f;

        twt[v - 1][0] = __fmul_rn(__fmul_rn(wx0, wy0), __fmul_rn(vx0, vy0));
        twt[v - 1][1] = __fmul_rn(__fmul_rn(wx1, wy0), __fmul_rn(vx1, vy0));
        twt[v - 1][2] = __fmul_rn(__fmul_rn(wx0, wy1), __fmul_rn(vx0, vy1));
        twt[v - 1][3] = __fmul_rn(__fmul_rn(wx1, wy1), __fmul_rn(vx1, vy1));

        int xi0 = (int)fminf(fmaxf(x0, 0.0f), (float)(W - 1));
        int xi1 = (int)fminf(fmaxf(x1, 0.0f), (float)(W - 1));
        int yi0 = (int)fminf(fmaxf(y0, 0.0f), (float)(H - 1));
        int yi1 = (int)fminf(fmaxf(y1, 0.0f), (float)(H - 1));

        int vb = (b * V + v) * C * HW;  // < 2^25, int32-safe
        toff[v - 1][0] = vb + yi0 * W + xi0;
        toff[v - 1][1] = vb + yi0 * W + xi1;
        toff[v - 1][2] = vb + yi1 * W + xi0;
        toff[v - 1][3] = vb + yi1 * W + xi1;
    }

    const int rb = b * V * C * HW + hw;  // ref view, c=0 plane
    const float inv_v = 1.0f / (float)V;
    // out layout [B,C,D,H,W]: ((b*C + c)*D + d)*HW + hw
    const size_t obase = ((size_t)b * C * D + d) * HW + (size_t)hw;

    int nzmask = 0;  // bit v set iff any channel of view v+1 sampled nonzero

#pragma unroll 2
    for (int c = 0; c < C; c++) {
        const int cofs = c * HW;
        // 17 independent loads; R1's per-instruction pattern (64 consecutive
        // same-d pixels). The block's 4 depth-waves touch near-identical
        // lines -> cross-d dedup in this CU's L1 instead of 4x HBM refetch.
        float rv = feats[rb + cofs];
        float s = rv;
        float q = rv * rv;
#pragma unroll
        for (int v = 0; v < V - 1; v++) {
            float f00 = feats[toff[v][0] + cofs];
            float f10 = feats[toff[v][1] + cofs];
            float f01 = feats[toff[v][2] + cofs];
            float f11 = feats[toff[v][3] + cofs];
            // zeroness is weight-structural (all-OOB => all wt exactly 0)
            float val = twt[v][0] * f00 + twt[v][1] * f10 + twt[v][2] * f01 + twt[v][3] * f11;
            nzmask |= (val != 0.0f) ? (1 << v) : 0;
            s += val;
            q += val * val;
        }
        // variance = sq/V - (sum/V)^2
        float sm = s * inv_v;
        float vv = q * inv_v - sm * sm;
        // streaming output, full 256B-per-wave lines: NT keeps it out of L2
        __builtin_nontemporal_store(vv, &var_out[obase + (size_t)c * (D * HW)]);
    }

    // cv_mask[b,h,w] = sum over (v,d) of any-channel-nonzero.
    // The 4 depth-waves of this pixel live in this block: LDS reduce.
    __shared__ int smask[64];
    if (d == 0) smask[lane] = 0;
    __syncthreads();
    atomicAdd(&smask[lane], __popc(nzmask));  // LDS atomic, 4 adders/slot
    __syncthreads();
    if (d == 0) mask_out[(size_t)b * HW + hw] = (float)smask[lane];
}

extern "C" void kernel_launch(void* const* d_in, const int* in_sizes, int n_in,
                              void* d_out, int out_size, void* d_ws, size_t ws_size,
                              hipStream_t stream) {
    const float* feats = (const float*)d_in[0];
    const float* proj = (const float*)d_in[1];
    const float* depthv = (const float*)d_in[2];

    float* var = (float*)d_out;
    float* mask = var + (size_t)B * C * D * HW;

    setup_proj<<<1, 64, 0, stream>>>(proj);

    warp_var<<<NBLK, BLK, 0, stream>>>(feats, depthv, var, mask);
}

// Round 6
// 271.722 us; speedup vs baseline: 1.3256x; 1.0153x over previous
//
#include <hip/hip_runtime.h>

// Problem constants (from setup_inputs)
constexpr int B = 2, V = 5, C = 32, H = 256, W = 320, D = 4;
constexpr int HW = H * W;
constexpr int BLK = 256;               // 4 waves = 4 depth planes
constexpr int NBLK = B * HW / 64;      // 2560 chunks of 64 pixels; %8==0

// 8-byte tap pair with 4-byte alignment guarantee (column is arbitrary).
// gfx950 supports unaligned global loads -> compiler may emit dwordx2;
// worst case it splits into two dwords (== old behavior, minus addr VALU).
typedef float f2_t __attribute__((ext_vector_type(2), aligned(4)));

// rot (9) + trans (3) per (b, src view v=1..4), fp32 (bit-exact ref replication)
__device__ float g_rt[B * (V - 1) * 12];

// combine(): upd = K3 @ E[:3,:4]. XLA-CPU naive small-dot emitter semantics.
__device__ void combine_np(const float* __restrict__ proj, int b, int v, float Mo[4][4]) {
    const float* E = proj + ((size_t)(b * V + v) * 2 + 0) * 16;
    const float* K = proj + ((size_t)(b * V + v) * 2 + 1) * 16;
    for (int i = 0; i < 3; i++)
        for (int j = 0; j < 4; j++) {
            float acc = __fadd_rn(0.0f, __fmul_rn(K[i * 4 + 0], E[0 * 4 + j]));
            acc = __fadd_rn(acc, __fmul_rn(K[i * 4 + 1], E[1 * 4 + j]));
            acc = __fadd_rn(acc, __fmul_rn(K[i * 4 + 2], E[2 * 4 + j]));
            Mo[i][j] = acc;
        }
    for (int j = 0; j < 4; j++) Mo[3][j] = E[3 * 4 + j];
}

// ---------------------------------------------------------------------------
// Setup (unchanged, bit-exact strti2 + naive-emitter chains).
// ---------------------------------------------------------------------------
__global__ void setup_proj(const float* __restrict__ proj) {
    int t = threadIdx.x;
    if (t >= B * (V - 1)) return;
    int b = t / (V - 1);
    int v = t % (V - 1) + 1;

    float R[4][4], S[4][4];
    combine_np(proj, b, 0, R);
    combine_np(proj, b, v, S);

    float I4[4][4];
    for (int i = 0; i < 4; i++)
        for (int j = 0; j < 4; j++) I4[i][j] = 0.0f;

    float d0 = __fdiv_rn(1.0f, R[0][0]);
    I4[0][0] = d0;
    float d1 = __fdiv_rn(1.0f, R[1][1]);
    I4[1][1] = d1;
    {
        float x0 = R[0][1];
        if (x0 != 0.0f) x0 = __fmul_rn(x0, I4[0][0]);
        I4[0][1] = __fmul_rn(x0, -d1);
    }
    float d2 = __fdiv_rn(1.0f, R[2][2]);
    I4[2][2] = d2;
    {
        float x0 = R[0][2], x1 = R[1][2];
        if (x0 != 0.0f) x0 = __fmul_rn(x0, I4[0][0]);
        if (x1 != 0.0f) {
            x0 = __fadd_rn(x0, __fmul_rn(x1, I4[0][1]));
            x1 = __fmul_rn(x1, I4[1][1]);
        }
        I4[0][2] = __fmul_rn(x0, -d2);
        I4[1][2] = __fmul_rn(x1, -d2);
    }
    float d3 = __fdiv_rn(1.0f, R[3][3]);
    I4[3][3] = d3;
    {
        float x0 = R[0][3], x1 = R[1][3], x2 = R[2][3];
        if (x0 != 0.0f) x0 = __fmul_rn(x0, I4[0][0]);
        if (x1 != 0.0f) {
            x0 = __fadd_rn(x0, __fmul_rn(x1, I4[0][1]));
            x1 = __fmul_rn(x1, I4[1][1]);
        }
        if (x2 != 0.0f) {
            x0 = __fadd_rn(x0, __fmul_rn(x2, I4[0][2]));
            x1 = __fadd_rn(x1, __fmul_rn(x2, I4[1][2]));
            x2 = __fmul_rn(x2, I4[2][2]);
        }
        I4[0][3] = __fmul_rn(x0, -d3);
        I4[1][3] = __fmul_rn(x1, -d3);
        I4[2][3] = __fmul_rn(x2, -d3);
    }

    float P[3][4];
    for (int i = 0; i < 3; i++)
        for (int k = 0; k < 4; k++) {
            float acc = 0.0f;
            for (int j = 0; j < 4; j++)
                acc = __fadd_rn(acc, __fmul_rn(S[i][j], I4[j][k]));
            P[i][k] = acc;
        }

    float* out = g_rt + t * 12;
    out[0] = P[0][0]; out[1] = P[0][1]; out[2] = P[0][2];
    out[3] = P[1][0]; out[4] = P[1][1]; out[5] = P[1][2];
    out[6] = P[2][0]; out[7] = P[2][1]; out[8] = P[2][2];
    out[9] = P[0][3]; out[10] = P[1][3]; out[11] = P[2][3];
}

// ---------------------------------------------------------------------------
// R5 (resubmit after infra failure): attack the VMEM request path.
// Evidence: R1 (396MB fetch) and R4 (55MB) both pin at ~149us -> NOT
// traffic-bound at any cache level. The invariant is the instruction
// stream: 17 scalar gathers + 1 store per c-iter (~88 cache-line
// transactions per wave per c-iter through TA/TCP) + 44% VALU. R3 (2.5x
// lines/instr) = 1.6x time corroborates a line-transaction wall blended
// with a VALU floor.
// Change: merge each view's x-tap pair (columns xi0, xi0+1 - adjacent
// floats) into ONE float2 gather per source row. Adjacent lanes' pairs
// overlap, so the pair-load's wave footprint (~65px ~ 5-6 lines) equals the
// old single-tap load -> tap TCP line-work HALVES (~88 -> ~48 lines/c-iter);
// VMEM instrs 18 -> 10 per c-iter; ~16 addr-VALU saved per c-iter.
// Edge handling via PRE-SWAPPED WEIGHTS (prologue-only cost): pair loads at
// colbase = min(xi0, W-2) (always in-row -> never OOB; max index is
// vb + C*HW - 1). When xi0==xi1 (x-clamped at 0 or W-1), the two taps read
// one element e and the pair weight collapses to (s00+s10) on the correct
// lane of the pair: s00*e + s10*e -> (s00+s10)*e (both nonneg, no
// cancellation, <=1ulp, zero/nonzero mask semantics preserved; only
// boundary-clamped pixels).
// Everything else (R4's d-waves-per-block mapping, XCD swizzle, LDS mask
// reduce, NT full-line stores) kept.
// ---------------------------------------------------------------------------
__global__ __launch_bounds__(256) void warp_var(
    const float* __restrict__ feats,
    const float* __restrict__ depthv,
    float* __restrict__ var_out,
    float* __restrict__ mask_out)
{
    // chunk-contiguous bijective XCD swizzle (NBLK % 8 == 0)
    int bid = blockIdx.x;
    int chunk = (bid & 7) * (NBLK / 8) + (bid >> 3);

    int lane = threadIdx.x & 63;
    int d = threadIdx.x >> 6;        // wave index == depth plane
    int pix = chunk * 64 + lane;     // global pixel in [0, B*HW)
    int hw = pix % HW;
    int b = pix / HW;
    int w = hw % W;
    int h = hw / W;

    float depth = depthv[(size_t)(b * D + d) * HW + hw];

    const float xf = (float)w, yf = (float)h;
    const float hwX = 0.5f * (float)(W - 1);  // 159.5
    const float hwY = 0.5f * (float)(H - 1);  // 127.5
    const float rcpX = 1.0f / 159.5f;  // fl(1/159.5), compile-time RN fold
    const float rcpY = 1.0f / 127.5f;  // fl(1/127.5)

    // Per-view tap state: 2 row offsets (at colbase, c=0 plane) + 4
    // pre-swapped pair weights {a00,a10,a01,a11}.
    int   toff[V - 1][2];
    float twt[V - 1][4];

#pragma unroll
    for (int v = 1; v < V; v++) {
        const float* P = g_rt + ((size_t)b * (V - 1) + (v - 1)) * 12;
        // Eigen FMA sweeps: fma(P1,y, fma(P0,x, 0)) then fma(P2,1,acc)=fadd
        float rx = __fadd_rn(__fmaf_rn(P[1], yf, __fmul_rn(P[0], xf)), P[2]);
        float ry = __fadd_rn(__fmaf_rn(P[4], yf, __fmul_rn(P[3], xf)), P[5]);
        float rz = __fadd_rn(__fmaf_rn(P[7], yf, __fmul_rn(P[6], xf)), P[8]);
        // pxyz = rot_xyz * d + trans : two separate ops (no contract FMF)
        float px = __fadd_rn(__fmul_rn(rx, depth), P[9]);
        float py = __fadd_rn(__fmul_rn(ry, depth), P[10]);
        float pz = __fadd_rn(__fmul_rn(rz, depth), P[11]);
        float gx = __fdiv_rn(px, pz);
        float gy = __fdiv_rn(py, pz);
        // XLA: divide-by-constant -> multiply-by-folded-reciprocal
        float nx = __fadd_rn(__fmul_rn(gx, rcpX), -1.0f);
        float ny = __fadd_rn(__fmul_rn(gy, rcpY), -1.0f);
        // round trip kept intact (no float reassociation by default)
        float x = __fmul_rn(__fadd_rn(nx, 1.0f), hwX);
        float y = __fmul_rn(__fadd_rn(ny, 1.0f), hwY);

        float x0 = floorf(x), y0 = floorf(y);
        float x1 = x0 + 1.0f, y1 = y0 + 1.0f;

        float wx0 = __fadd_rn(1.0f, -fabsf(__fadd_rn(x, -x0)));
        float wx1 = __fadd_rn(1.0f, -fabsf(__fadd_rn(x, -x1)));
        float wy0 = __fadd_rn(1.0f, -fabsf(__fadd_rn(y, -y0)));
        float wy1 = __fadd_rn(1.0f, -fabsf(__fadd_rn(y, -y1)));

        float vx0 = (x0 >= 0.0f && x0 <= (float)(W - 1)) ? 1.0f : 0.0f;
        float vx1 = (x1 >= 0.0f && x1 <= (float)(W - 1)) ? 1.0f : 0.0f;
        float vy0 = (y0 >= 0.0f && y0 <= (float)(H - 1)) ? 1.0f : 0.0f;
        float vy1 = (y1 >= 0.0f && y1 <= (float)(H - 1)) ? 1.0f : 0.0f;

        float s00 = __fmul_rn(__fmul_rn(wx0, wy0), __fmul_rn(vx0, vy0));
        float s10 = __fmul_rn(__fmul_rn(wx1, wy0), __fmul_rn(vx1, vy0));
        float s01 = __fmul_rn(__fmul_rn(wx0, wy1), __fmul_rn(vx0, vy1));
        float s11 = __fmul_rn(__fmul_rn(wx1, wy1), __fmul_rn(vx1, vy1));

        int xi0 = (int)fminf(fmaxf(x0, 0.0f), (float)(W - 1));
        int xi1 = (int)fminf(fmaxf(x1, 0.0f), (float)(W - 1));
        int yi0 = (int)fminf(fmaxf(y0, 0.0f), (float)(H - 1));
        int yi1 = (int)fminf(fmaxf(y1, 0.0f), (float)(H - 1));

        // Pair geometry: load [colbase, colbase+1], always in-row.
        int colbase = min(xi0, W - 2);
        // Pre-swapped weights. xi0==xi1 only via clamping (x0<=-1 -> both 0;
        // x0>=W-1 -> both W-1). Interior: colbase==xi0, pair = (xi0, xi1).
        bool eq = (xi0 == xi1);
        bool lo = (xi0 == 0);
        float sx0 = __fadd_rn(s00, s10);  // used only in eq case
        float sx1 = __fadd_rn(s01, s11);
        float a00 = eq ? (lo ? sx0 : 0.0f) : s00;
        float a10 = eq ? (lo ? 0.0f : sx0) : s10;
        float a01 = eq ? (lo ? sx1 : 0.0f) : s01;
        float a11 = eq ? (lo ? 0.0f : sx1) : s11;

        twt[v - 1][0] = a00;
        twt[v - 1][1] = a10;
        twt[v - 1][2] = a01;
        twt[v - 1][3] = a11;

        int vb = (b * V + v) * C * HW;  // < 2^25, int32-safe
        toff[v - 1][0] = vb + yi0 * W + colbase;
        toff[v - 1][1] = vb + yi1 * W + colbase;
    }

    const int rb = b * V * C * HW + hw;  // ref view, c=0 plane
    const float inv_v = 1.0f / (float)V;
    // out layout [B,C,D,H,W]: ((b*C + c)*D + d)*HW + hw
    const size_t obase = ((size_t)b * C * D + d) * HW + (size_t)hw;

    int nzmask = 0;  // bit v set iff any channel of view v+1 sampled nonzero

#pragma unroll 2
    for (int c = 0; c < C; c++) {
        const int cofs = c * HW;
        // 9 independent VMEM ops (1 ref dword + 8 pair dwordx2), ~48 line
        // transactions per wave (was 17 ops / ~88 lines).
        float rv = feats[rb + cofs];
        float s = rv;
        float q = rv * rv;
#pragma unroll
        for (int v = 0; v < V - 1; v++) {
            f2_t p0 = *reinterpret_cast<const f2_t*>(feats + toff[v][0] + cofs);
            f2_t p1 = *reinterpret_cast<const f2_t*>(feats + toff[v][1] + cofs);
            // same left-assoc order as the scalar version
            float val = twt[v][0] * p0.x + twt[v][1] * p0.y
                      + twt[v][2] * p1.x + twt[v][3] * p1.y;
            nzmask |= (val != 0.0f) ? (1 << v) : 0;
            s += val;
            q += val * val;
        }
        // variance = sq/V - (sum/V)^2
        float sm = s * inv_v;
        float vv = q * inv_v - sm * sm;
        // streaming output, full 256B-per-wave lines: NT keeps it out of L2
        __builtin_nontemporal_store(vv, &var_out[obase + (size_t)c * (D * HW)]);
    }

    // cv_mask[b,h,w] = sum over (v,d) of any-channel-nonzero.
    // The 4 depth-waves of this pixel live in this block: LDS reduce.
    __shared__ int smask[64];
    if (d == 0) smask[lane] = 0;
    __syncthreads();
    atomicAdd(&smask[lane], __popc(nzmask));  // LDS atomic, 4 adders/slot
    __syncthreads();
    if (d == 0) mask_out[(size_t)b * HW + hw] = (float)smask[lane];
}

extern "C" void kernel_launch(void* const* d_in, const int* in_sizes, int n_in,
                              void* d_out, int out_size, void* d_ws, size_t ws_size,
                              hipStream_t stream) {
    const float* feats = (const float*)d_in[0];
    const float* proj = (const float*)d_in[1];
    const float* depthv = (const float*)d_in[2];

    float* var = (float*)d_out;
    float* mask = var + (size_t)B * C * D * HW;

    setup_proj<<<1, 64, 0, stream>>>(proj);

    warp_var<<<NBLK, BLK, 0, stream>>>(feats, depthv, var, mask);
}